// Round 1
// baseline (7004.860 us; speedup 1.0000x reference)
//
#include <hip/hip_runtime.h>
#include <hip/hip_bf16.h>

// LiquidLinear: xin = x@Wi^T + bi ; scan: h' = (1-sig(tau))h + sig(tau)tanh(xin_t + h@Wr^T + br)
// outs = hs@Wo^T + bo ; outputs = [outs (B,S,DOUT) fp32][h_final (B,H) fp32]
// B=64 S=1024 DIN=H=DOUT=512
//
// Plan: GEMM1 (xin, stored fp32 in the d_out "outs" region, overwritten later by GEMM3),
//       scan kernel: 4 groups x 4 col-slices = 16 WGs, Wr register-stationary bf16 frags,
//       h exchanged via parity-double-buffered global buffer + monotonic flags (agent atomics),
//       GEMM3 (outs from hs bf16 in workspace).

typedef short bf16x8 __attribute__((ext_vector_type(8)));
typedef float f32x4 __attribute__((ext_vector_type(4)));
typedef float floatv4 __attribute__((ext_vector_type(4)));
typedef unsigned short ushort4v __attribute__((ext_vector_type(4)));

#define B_ 64
#define S_ 1024
#define H_ 512
#define NSTEP 1024

__device__ __forceinline__ unsigned short f2bf(float f) {
    union { float f; unsigned u; } v; v.f = f;
    unsigned r = v.u + 0x7FFF + ((v.u >> 16) & 1);   // RNE
    return (unsigned short)(r >> 16);
}
__device__ __forceinline__ float bf2f(unsigned short u) {
    union { unsigned u; float f; } v; v.u = ((unsigned)u) << 16;
    return v.f;
}

// ---------------------------------------------------------------- init flags
__global__ void init_flags(int* flags) {
    if (threadIdx.x < 16) flags[threadIdx.x] = 0;
}

// ---------------------------------------------------------------- GEMM1: xin = x @ Wi^T + bi
// A = x fp32 [65536,512] row-major, B = Wi fp32 [512,512] row-major (K-contig both)
// C written to xin[t*64+b][n] fp32 where row r = b*1024+t
__global__ __launch_bounds__(256) void gemm_xin(
    const float* __restrict__ X, const float* __restrict__ Wi,
    const float* __restrict__ bi, float* __restrict__ xin)
{
    __shared__ unsigned short As[128][40];
    __shared__ unsigned short Bs[128][40];
    const int bm = blockIdx.x, bn = blockIdx.y;
    const int tid = threadIdx.x, w = tid >> 6, l = tid & 63;
    const int wm = w >> 1, wn = w & 1;
    f32x4 acc[4][4] = {};

    for (int kt = 0; kt < 512; kt += 32) {
        __syncthreads();
        // stage A and B tiles (fp32 -> bf16)
        #pragma unroll
        for (int j = 0; j < 4; j++) {
            int q = tid + 256 * j;            // 0..1023 float4-chunks
            int row = q >> 3, c4 = (q & 7) * 4;
            floatv4 va = *(const floatv4*)&X[(size_t)(bm * 128 + row) * 512 + kt + c4];
            floatv4 vb = *(const floatv4*)&Wi[(size_t)(bn * 128 + row) * 512 + kt + c4];
            ushort4v pa, pb;
            #pragma unroll
            for (int e = 0; e < 4; e++) { pa[e] = f2bf(va[e]); pb[e] = f2bf(vb[e]); }
            *(ushort4v*)&As[row][c4] = pa;
            *(ushort4v*)&Bs[row][c4] = pb;
        }
        __syncthreads();
        bf16x8 a[4], b[4];
        #pragma unroll
        for (int i = 0; i < 4; i++)
            a[i] = *(const bf16x8*)&As[wm * 64 + i * 16 + (l & 15)][(l >> 4) * 8];
        #pragma unroll
        for (int i = 0; i < 4; i++)
            b[i] = *(const bf16x8*)&Bs[wn * 64 + i * 16 + (l & 15)][(l >> 4) * 8];
        #pragma unroll
        for (int i = 0; i < 4; i++)
            #pragma unroll
            for (int j = 0; j < 4; j++)
                acc[i][j] = __builtin_amdgcn_mfma_f32_16x16x32_bf16(a[i], b[j], acc[i][j], 0, 0, 0);
    }
    #pragma unroll
    for (int i = 0; i < 4; i++)
        #pragma unroll
        for (int j = 0; j < 4; j++)
            #pragma unroll
            for (int r = 0; r < 4; r++) {
                int m = bm * 128 + wm * 64 + i * 16 + (l >> 4) * 4 + r;   // row in [B*S]
                int n = bn * 128 + wn * 64 + j * 16 + (l & 15);
                int bb = m >> 10, tt = m & 1023;
                xin[((size_t)tt * 64 + bb) * 512 + n] = acc[i][j][r] + bi[n];
            }
}

// ---------------------------------------------------------------- GEMM3: outs = hs @ Wo^T + bo
// A = hs bf16 [S,B,H] (row for out-row r=b*S+t is hs[(r&1023)*64 + (r>>10)])
__global__ __launch_bounds__(256) void gemm_out(
    const unsigned short* __restrict__ hs, const float* __restrict__ Wo,
    const float* __restrict__ bo, float* __restrict__ out)
{
    __shared__ unsigned short As[128][40];
    __shared__ unsigned short Bs[128][40];
    const int bm = blockIdx.x, bn = blockIdx.y;
    const int tid = threadIdx.x, w = tid >> 6, l = tid & 63;
    const int wm = w >> 1, wn = w & 1;
    f32x4 acc[4][4] = {};

    for (int kt = 0; kt < 512; kt += 32) {
        __syncthreads();
        // stage A (bf16 direct) : 512 chunks of 8
        #pragma unroll
        for (int j = 0; j < 2; j++) {
            int q = tid + 256 * j;            // 0..511
            int row = q >> 2, c8 = (q & 3) * 8;
            int r = bm * 128 + row;
            int ra = (r & 1023) * 64 + (r >> 10);
            bf16x8 v = *(const bf16x8*)&hs[(size_t)ra * 512 + kt + c8];
            *(bf16x8*)&As[row][c8] = v;
        }
        // stage B (fp32 -> bf16)
        #pragma unroll
        for (int j = 0; j < 4; j++) {
            int q = tid + 256 * j;
            int row = q >> 3, c4 = (q & 7) * 4;
            floatv4 vb = *(const floatv4*)&Wo[(size_t)(bn * 128 + row) * 512 + kt + c4];
            ushort4v pb;
            #pragma unroll
            for (int e = 0; e < 4; e++) pb[e] = f2bf(vb[e]);
            *(ushort4v*)&Bs[row][c4] = pb;
        }
        __syncthreads();
        bf16x8 a[4], b[4];
        #pragma unroll
        for (int i = 0; i < 4; i++)
            a[i] = *(const bf16x8*)&As[wm * 64 + i * 16 + (l & 15)][(l >> 4) * 8];
        #pragma unroll
        for (int i = 0; i < 4; i++)
            b[i] = *(const bf16x8*)&Bs[wn * 64 + i * 16 + (l & 15)][(l >> 4) * 8];
        #pragma unroll
        for (int i = 0; i < 4; i++)
            #pragma unroll
            for (int j = 0; j < 4; j++)
                acc[i][j] = __builtin_amdgcn_mfma_f32_16x16x32_bf16(a[i], b[j], acc[i][j], 0, 0, 0);
    }
    #pragma unroll
    for (int i = 0; i < 4; i++)
        #pragma unroll
        for (int j = 0; j < 4; j++)
            #pragma unroll
            for (int r = 0; r < 4; r++) {
                int m = bm * 128 + wm * 64 + i * 16 + (l >> 4) * 4 + r;
                int n = bn * 128 + wn * 64 + j * 16 + (l & 15);
                out[(size_t)m * 512 + n] = acc[i][j][r] + bo[n];
            }
}

// ---------------------------------------------------------------- scan
// 16 WGs: group g = bid>>2 (16 batches), slice s = bid&3 (128 cols).
// Wr slice register-stationary as bf16 B-frags (64 VGPR/wave).
// h state: fp32 in regs (own elems) ; MFMA A = hi/lo bf16 from LDS.
// Exchange: hbuf[2][64][512] fp32 (parity slot), flags[16] monotonic (t+1).
__global__ __launch_bounds__(512, 2) void scan_k(
    const float* __restrict__ Wr, const float* __restrict__ brv,
    const float* __restrict__ tau, const float* __restrict__ xin,
    unsigned short* __restrict__ hs, float* __restrict__ hbuf,
    int* __restrict__ flags, float* __restrict__ hfinal)
{
    const int g = blockIdx.x >> 2;
    const int s = blockIdx.x & 3;
    const int tid = threadIdx.x, w = tid >> 6, l = tid & 63;

    __shared__ unsigned short hHi[16][520];
    __shared__ unsigned short hLo[16][520];
    for (int i = tid; i < 16 * 520; i += 512) {
        (&hHi[0][0])[i] = 0; (&hLo[0][0])[i] = 0;
    }

    // register-stationary Wr slice: wave owns 16 cols, lane col j
    const int j = s * 128 + w * 16 + (l & 15);
    bf16x8 wf[16];
    #pragma unroll
    for (int kt = 0; kt < 16; kt++) {
        const float* p = &Wr[(size_t)j * 512 + kt * 32 + (l >> 4) * 8];
        bf16x8 f;
        #pragma unroll
        for (int e = 0; e < 8; e++) f[e] = (short)f2bf(p[e]);
        wf[kt] = f;
    }
    const float dj = 1.f / (1.f + __expf(-tau[j]));
    const float dj1 = 1.f - dj;
    const float brj = brv[j];
    float hold[4] = {0.f, 0.f, 0.f, 0.f};
    __syncthreads();

    for (int t = 0; t < NSTEP; ++t) {
        // prefetch xin for this step (independent of h -> hides under MFMA)
        float xv[4];
        #pragma unroll
        for (int r = 0; r < 4; r++) {
            int m = (l >> 4) * 4 + r;
            xv[r] = xin[((size_t)t * 64 + g * 16 + m) * 512 + j];
        }
        // MFMA: I_slice = h @ WrSlice^T  (hi + lo passes, independent acc chains)
        f32x4 accA = {0.f, 0.f, 0.f, 0.f}, accB = {0.f, 0.f, 0.f, 0.f};
        #pragma unroll
        for (int kt = 0; kt < 16; kt++) {
            const int row = l & 15, k = kt * 32 + (l >> 4) * 8;
            bf16x8 ah = *(const bf16x8*)&hHi[row][k];
            bf16x8 al = *(const bf16x8*)&hLo[row][k];
            accA = __builtin_amdgcn_mfma_f32_16x16x32_bf16(ah, wf[kt], accA, 0, 0, 0);
            accB = __builtin_amdgcn_mfma_f32_16x16x32_bf16(al, wf[kt], accB, 0, 0, 0);
        }
        const int par = (t + 1) & 1;
        __syncthreads();   // all waves done reading LDS h_t

        float hnew[4];
        #pragma unroll
        for (int r = 0; r < 4; r++) {
            float I = accA[r] + accB[r] + xv[r] + brj;
            float sv = tanhf(I);
            float hn = dj1 * hold[r] + dj * sv;
            hold[r] = hn; hnew[r] = hn;
            int m = (l >> 4) * 4 + r;
            hs[((size_t)t * 64 + g * 16 + m) * 512 + j] = f2bf(hn);
        }
        if (t == NSTEP - 1) {
            #pragma unroll
            for (int r = 0; r < 4; r++) {
                int m = (l >> 4) * 4 + r;
                hfinal[(size_t)(g * 16 + m) * 512 + j] = hold[r];
            }
            break;
        }
        // publish own slice (agent-coherent stores)
        #pragma unroll
        for (int r = 0; r < 4; r++) {
            int m = (l >> 4) * 4 + r;
            __hip_atomic_store(&hbuf[((size_t)par * 64 + g * 16 + m) * 512 + j], hnew[r],
                               __ATOMIC_RELAXED, __HIP_MEMORY_SCOPE_AGENT);
        }
        // own slice into LDS (hi/lo)
        #pragma unroll
        for (int r = 0; r < 4; r++) {
            int m = (l >> 4) * 4 + r;
            unsigned short hi = f2bf(hnew[r]);
            unsigned short lo = f2bf(hnew[r] - bf2f(hi));
            hHi[m][j] = hi; hLo[m][j] = lo;
        }
        __syncthreads();   // drains vmcnt(0): hbuf stores complete before flag
        if (tid == 0) {
            __threadfence();
            __hip_atomic_store(&flags[g * 4 + s], t + 1,
                               __ATOMIC_RELEASE, __HIP_MEMORY_SCOPE_AGENT);
        }
        if (tid < 4 && tid != s) {
            while (__hip_atomic_load(&flags[g * 4 + tid],
                                     __ATOMIC_ACQUIRE, __HIP_MEMORY_SCOPE_AGENT) < t + 1) {
                __builtin_amdgcn_s_sleep(1);
            }
        }
        __syncthreads();
        // read 3 peer slices: 16 rows x 384 cols = 6144 elems = 12/thread
        #pragma unroll
        for (int i = 0; i < 12; i++) {
            int e = tid + 512 * i;
            int row = e / 384, cc = e - row * 384;
            int col = cc + (cc >= s * 128 ? 128 : 0);
            float v = __hip_atomic_load(&hbuf[((size_t)par * 64 + g * 16 + row) * 512 + col],
                                        __ATOMIC_RELAXED, __HIP_MEMORY_SCOPE_AGENT);
            unsigned short hi = f2bf(v);
            unsigned short lo = f2bf(v - bf2f(hi));
            hHi[row][col] = hi; hLo[row][col] = lo;
        }
        __syncthreads();   // LDS h_{t+1} ready
    }
}

// ---------------------------------------------------------------- launch
extern "C" void kernel_launch(void* const* d_in, const int* in_sizes, int n_in,
                              void* d_out, int out_size, void* d_ws, size_t ws_size,
                              hipStream_t stream) {
    const float* x   = (const float*)d_in[0];
    const float* Wi  = (const float*)d_in[1];
    const float* bi  = (const float*)d_in[2];
    const float* Wr  = (const float*)d_in[3];
    const float* br  = (const float*)d_in[4];
    const float* tau = (const float*)d_in[5];
    const float* Wo  = (const float*)d_in[6];
    const float* bo  = (const float*)d_in[7];

    float* out    = (float*)d_out;
    float* xin    = (float*)d_out;                       // reuse outs region for xin [S,B,H] fp32
    float* hfinal = (float*)d_out + (size_t)33554432;    // B*S*DOUT

    // workspace: hs bf16 [S,B,H] (64MiB) | hbuf fp32 [2][64][512] | flags[16]
    unsigned short* hs = (unsigned short*)d_ws;
    float* hbuf = (float*)((char*)d_ws + (size_t)67108864);
    int* flags  = (int*)((char*)d_ws + (size_t)67108864 + 262144);

    hipLaunchKernelGGL(init_flags, dim3(1), dim3(64), 0, stream, flags);
    hipLaunchKernelGGL(gemm_xin, dim3(512, 4), dim3(256), 0, stream, x, Wi, bi, xin);
    hipLaunchKernelGGL(scan_k, dim3(16), dim3(512), 0, stream,
                       Wr, br, tau, xin, hs, hbuf, flags, hfinal);
    hipLaunchKernelGGL(gemm_out, dim3(512, 4), dim3(256), 0, stream, hs, Wo, bo, out);
}

// Round 4
// 6075.883 us; speedup vs baseline: 1.1529x; 1.1529x over previous
//
#include <hip/hip_runtime.h>
#include <hip/hip_bf16.h>

// LiquidLinear: xin = x@Wi^T + bi ; scan: h' = (1-sig(tau))h + sig(tau)tanh(xin_t + h@Wr^T + br)
// outs = hs@Wo^T + bo ; outputs = [outs (B,S,DOUT) fp32][h_final (B,H) fp32]
// B=64 S=1024 DIN=H=DOUT=512
//
// R4: R3 structure (8 blocks = 4 groups x 2 col-slices, Wr register-stationary
// 128 VGPR/wave, packed hi/lo u64 exchange) but with COMPILER atomics for all
// cross-block traffic (R1-proven): relaxed agent stores for data, per-wave
// RELEASE flag store (vmcnt is per-wave -> lane0's release orders the wave's
// prior stores), ACQUIRE flag polls (progress + orders subsequent data loads),
// relaxed data loads. R3's hand-rolled sc0sc1 ops lacked wbl2/inv maintenance
// and read stale L2 lines -> wrong data. No XCD handshake (R2 deadlock).

typedef short bf16x8 __attribute__((ext_vector_type(8)));
typedef float f32x4 __attribute__((ext_vector_type(4)));
typedef float floatv4 __attribute__((ext_vector_type(4)));
typedef unsigned short ushort4v __attribute__((ext_vector_type(4)));

#define NSTEP 1024

__device__ __forceinline__ unsigned short f2bf(float f) {
    union { float f; unsigned u; } v; v.f = f;
    unsigned r = v.u + 0x7FFF + ((v.u >> 16) & 1);   // RNE
    return (unsigned short)(r >> 16);
}
__device__ __forceinline__ float bf2f(unsigned short u) {
    union { unsigned u; float f; } v; v.u = ((unsigned)u) << 16;
    return v.f;
}

// ---------------------------------------------------------------- init control memory
__global__ void init_flags(int* flags) {
    int i = threadIdx.x;
    if (i < 64) flags[i] = 0;   // kernel-boundary coherence makes these visible
}

// ---------------------------------------------------------------- GEMM1: xin = x @ Wi^T + bi
__global__ __launch_bounds__(256) void gemm_xin(
    const float* __restrict__ X, const float* __restrict__ Wi,
    const float* __restrict__ bi, float* __restrict__ xin)
{
    __shared__ unsigned short As[128][40];
    __shared__ unsigned short Bs[128][40];
    const int bm = blockIdx.x, bn = blockIdx.y;
    const int tid = threadIdx.x, w = tid >> 6, l = tid & 63;
    const int wm = w >> 1, wn = w & 1;
    f32x4 acc[4][4] = {};

    for (int kt = 0; kt < 512; kt += 32) {
        __syncthreads();
        #pragma unroll
        for (int j = 0; j < 4; j++) {
            int q = tid + 256 * j;
            int row = q >> 3, c4 = (q & 7) * 4;
            floatv4 va = *(const floatv4*)&X[(size_t)(bm * 128 + row) * 512 + kt + c4];
            floatv4 vb = *(const floatv4*)&Wi[(size_t)(bn * 128 + row) * 512 + kt + c4];
            ushort4v pa, pb;
            #pragma unroll
            for (int e = 0; e < 4; e++) { pa[e] = f2bf(va[e]); pb[e] = f2bf(vb[e]); }
            *(ushort4v*)&As[row][c4] = pa;
            *(ushort4v*)&Bs[row][c4] = pb;
        }
        __syncthreads();
        bf16x8 a[4], b[4];
        #pragma unroll
        for (int i = 0; i < 4; i++)
            a[i] = *(const bf16x8*)&As[wm * 64 + i * 16 + (l & 15)][(l >> 4) * 8];
        #pragma unroll
        for (int i = 0; i < 4; i++)
            b[i] = *(const bf16x8*)&Bs[wn * 64 + i * 16 + (l & 15)][(l >> 4) * 8];
        #pragma unroll
        for (int i = 0; i < 4; i++)
            #pragma unroll
            for (int j = 0; j < 4; j++)
                acc[i][j] = __builtin_amdgcn_mfma_f32_16x16x32_bf16(a[i], b[j], acc[i][j], 0, 0, 0);
    }
    #pragma unroll
    for (int i = 0; i < 4; i++)
        #pragma unroll
        for (int j = 0; j < 4; j++)
            #pragma unroll
            for (int r = 0; r < 4; r++) {
                int m = bm * 128 + wm * 64 + i * 16 + (l >> 4) * 4 + r;
                int n = bn * 128 + wn * 64 + j * 16 + (l & 15);
                int bb = m >> 10, tt = m & 1023;
                xin[((size_t)tt * 64 + bb) * 512 + n] = acc[i][j][r] + bi[n];
            }
}

// ---------------------------------------------------------------- GEMM3: outs = hs @ Wo^T + bo
__global__ __launch_bounds__(256) void gemm_out(
    const unsigned short* __restrict__ hs, const float* __restrict__ Wo,
    const float* __restrict__ bo, float* __restrict__ out)
{
    __shared__ unsigned short As[128][40];
    __shared__ unsigned short Bs[128][40];
    const int bm = blockIdx.x, bn = blockIdx.y;
    const int tid = threadIdx.x, w = tid >> 6, l = tid & 63;
    const int wm = w >> 1, wn = w & 1;
    f32x4 acc[4][4] = {};

    for (int kt = 0; kt < 512; kt += 32) {
        __syncthreads();
        #pragma unroll
        for (int j = 0; j < 2; j++) {
            int q = tid + 256 * j;
            int row = q >> 2, c8 = (q & 3) * 8;
            int r = bm * 128 + row;
            int ra = (r & 1023) * 64 + (r >> 10);
            bf16x8 v = *(const bf16x8*)&hs[(size_t)ra * 512 + kt + c8];
            *(bf16x8*)&As[row][c8] = v;
        }
        #pragma unroll
        for (int j = 0; j < 4; j++) {
            int q = tid + 256 * j;
            int row = q >> 3, c4 = (q & 7) * 4;
            floatv4 vb = *(const floatv4*)&Wo[(size_t)(bn * 128 + row) * 512 + kt + c4];
            ushort4v pb;
            #pragma unroll
            for (int e = 0; e < 4; e++) pb[e] = f2bf(vb[e]);
            *(ushort4v*)&Bs[row][c4] = pb;
        }
        __syncthreads();
        bf16x8 a[4], b[4];
        #pragma unroll
        for (int i = 0; i < 4; i++)
            a[i] = *(const bf16x8*)&As[wm * 64 + i * 16 + (l & 15)][(l >> 4) * 8];
        #pragma unroll
        for (int i = 0; i < 4; i++)
            b[i] = *(const bf16x8*)&Bs[wn * 64 + i * 16 + (l & 15)][(l >> 4) * 8];
        #pragma unroll
        for (int i = 0; i < 4; i++)
            #pragma unroll
            for (int j = 0; j < 4; j++)
                acc[i][j] = __builtin_amdgcn_mfma_f32_16x16x32_bf16(a[i], b[j], acc[i][j], 0, 0, 0);
    }
    #pragma unroll
    for (int i = 0; i < 4; i++)
        #pragma unroll
        for (int j = 0; j < 4; j++)
            #pragma unroll
            for (int r = 0; r < 4; r++) {
                int m = bm * 128 + wm * 64 + i * 16 + (l >> 4) * 4 + r;
                int n = bn * 128 + wn * 64 + j * 16 + (l & 15);
                out[(size_t)m * 512 + n] = acc[i][j][r] + bo[n];
            }
}

// ---------------------------------------------------------------- scan
// 8 blocks: group g = bid&3 (16 batches), slice sl = bid>>2 (256 cols).
// hbuf64: u64 [4 group][2 par][512 col][8 rowpair]; value = rows (2rp,2rp+1)
// each packed (bf16hi<<16)|bf16lo. flags[(g*2+sl)*8+wave] monotonic counters.
__global__ __launch_bounds__(512, 2) void scan_k(
    const float* __restrict__ Wr, const float* __restrict__ brv,
    const float* __restrict__ tau, const float* __restrict__ xin,
    unsigned short* __restrict__ hs, unsigned long long* __restrict__ hbuf64,
    int* __restrict__ flags, float* __restrict__ hfinal)
{
    const int g  = blockIdx.x & 3;
    const int sl = blockIdx.x >> 2;      // 0..1
    const int tid = threadIdx.x, w = tid >> 6, l = tid & 63;

    __shared__ unsigned short hHi[16][520];
    __shared__ unsigned short hLo[16][520];
    for (int i = tid; i < 16 * 520; i += 512) { (&hHi[0][0])[i] = 0; (&hLo[0][0])[i] = 0; }

    // register-stationary Wr slice: wave owns 32 cols (two 16-col MFMA n-tiles)
    const int j0 = sl * 256 + w * 32 + (l & 15);
    const int j1 = j0 + 16;
    bf16x8 wf0[16], wf1[16];
    #pragma unroll
    for (int kt = 0; kt < 16; kt++) {
        const float* p0 = &Wr[(size_t)j0 * 512 + kt * 32 + (l >> 4) * 8];
        const float* p1 = &Wr[(size_t)j1 * 512 + kt * 32 + (l >> 4) * 8];
        bf16x8 f0, f1;
        #pragma unroll
        for (int e = 0; e < 8; e++) { f0[e] = (short)f2bf(p0[e]); f1[e] = (short)f2bf(p1[e]); }
        wf0[kt] = f0; wf1[kt] = f1;
    }
    const float d0 = 1.f / (1.f + __expf(-tau[j0])), d0c = 1.f - d0, br0 = brv[j0];
    const float d1 = 1.f / (1.f + __expf(-tau[j1])), d1c = 1.f - d1, br1 = brv[j1];
    float hold0[4] = {}, hold1[4] = {};
    const int mr4 = (l >> 4) * 4;             // this thread's 4 batch rows (local 0..15)
    const int p1i = 1 - sl;

    __syncthreads();

    // prologue xin for t=0
    float xv0[4], xv1[4], xn0[4], xn1[4];
    #pragma unroll
    for (int r = 0; r < 4; r++) {
        xv0[r] = xin[((size_t)0 * 64 + g * 16 + mr4 + r) * 512 + j0];
        xv1[r] = xin[((size_t)0 * 64 + g * 16 + mr4 + r) * 512 + j1];
    }

    for (int t = 0; t < NSTEP; ++t) {
        // prefetch next-step xin early (HBM latency hides under MFMA phase)
        if (t + 1 < NSTEP) {
            #pragma unroll
            for (int r = 0; r < 4; r++) {
                xn0[r] = xin[((size_t)(t + 1) * 64 + g * 16 + mr4 + r) * 512 + j0];
                xn1[r] = xin[((size_t)(t + 1) * 64 + g * 16 + mr4 + r) * 512 + j1];
            }
        }
        // I = h @ WrSlice^T (hi + lo passes, 4 independent acc chains)
        f32x4 aA0 = {}, aB0 = {}, aA1 = {}, aB1 = {};
        #pragma unroll
        for (int kt = 0; kt < 16; kt++) {
            bf16x8 ah = *(const bf16x8*)&hHi[l & 15][kt * 32 + (l >> 4) * 8];
            bf16x8 al = *(const bf16x8*)&hLo[l & 15][kt * 32 + (l >> 4) * 8];
            aA0 = __builtin_amdgcn_mfma_f32_16x16x32_bf16(ah, wf0[kt], aA0, 0, 0, 0);
            aB0 = __builtin_amdgcn_mfma_f32_16x16x32_bf16(al, wf0[kt], aB0, 0, 0, 0);
            aA1 = __builtin_amdgcn_mfma_f32_16x16x32_bf16(ah, wf1[kt], aA1, 0, 0, 0);
            aB1 = __builtin_amdgcn_mfma_f32_16x16x32_bf16(al, wf1[kt], aB1, 0, 0, 0);
        }

        float hn0[4], hn1[4];
        #pragma unroll
        for (int r = 0; r < 4; r++) {
            float I0 = aA0[r] + aB0[r] + xv0[r] + br0;
            float I1 = aA1[r] + aB1[r] + xv1[r] + br1;
            hn0[r] = d0c * hold0[r] + d0 * tanhf(I0); hold0[r] = hn0[r];
            hn1[r] = d1c * hold1[r] + d1 * tanhf(I1); hold1[r] = hn1[r];
        }
        if (t == NSTEP - 1) {
            #pragma unroll
            for (int r = 0; r < 4; r++) {
                size_t row = (size_t)t * 64 + g * 16 + mr4 + r;
                hs[row * 512 + j0] = f2bf(hn0[r]);
                hs[row * 512 + j1] = f2bf(hn1[r]);
                hfinal[(size_t)(g * 16 + mr4 + r) * 512 + j0] = hold0[r];
                hfinal[(size_t)(g * 16 + mr4 + r) * 512 + j1] = hold1[r];
            }
            break;
        }
        const int par = (t + 1) & 1;

        // pack hi/lo
        unsigned pk0[4], pk1[4];
        #pragma unroll
        for (int r = 0; r < 4; r++) {
            unsigned short h0 = f2bf(hn0[r]), lo0 = f2bf(hn0[r] - bf2f(h0));
            unsigned short h1 = f2bf(hn1[r]), lo1 = f2bf(hn1[r] - bf2f(h1));
            pk0[r] = ((unsigned)h0 << 16) | lo0;
            pk1[r] = ((unsigned)h1 << 16) | lo1;
        }
        // publish own slice: 4 relaxed u64 agent stores (rows mr4..mr4+3)
        {
            unsigned long long q00 = (unsigned long long)pk0[0] | ((unsigned long long)pk0[1] << 32);
            unsigned long long q01 = (unsigned long long)pk0[2] | ((unsigned long long)pk0[3] << 32);
            unsigned long long q10 = (unsigned long long)pk1[0] | ((unsigned long long)pk1[1] << 32);
            unsigned long long q11 = (unsigned long long)pk1[2] | ((unsigned long long)pk1[3] << 32);
            size_t b0 = ((size_t)(g * 2 + par) * 512 + j0) * 8 + (mr4 >> 1);
            size_t b1 = ((size_t)(g * 2 + par) * 512 + j1) * 8 + (mr4 >> 1);
            __hip_atomic_store(&hbuf64[b0],     q00, __ATOMIC_RELAXED, __HIP_MEMORY_SCOPE_AGENT);
            __hip_atomic_store(&hbuf64[b0 + 1], q01, __ATOMIC_RELAXED, __HIP_MEMORY_SCOPE_AGENT);
            __hip_atomic_store(&hbuf64[b1],     q10, __ATOMIC_RELAXED, __HIP_MEMORY_SCOPE_AGENT);
            __hip_atomic_store(&hbuf64[b1 + 1], q11, __ATOMIC_RELAXED, __HIP_MEMORY_SCOPE_AGENT);
        }
        // per-wave release flag: orders THIS wave's 4 data stores (vmcnt is per-wave)
        if (l == 0)
            __hip_atomic_store(&flags[(g * 2 + sl) * 8 + w], t + 1,
                               __ATOMIC_RELEASE, __HIP_MEMORY_SCOPE_AGENT);

        __syncthreads();                       // all waves done reading LDS h_t
        // own slice into LDS
        #pragma unroll
        for (int r = 0; r < 4; r++) {
            hHi[mr4 + r][j0] = (unsigned short)(pk0[r] >> 16);
            hLo[mr4 + r][j0] = (unsigned short)(pk0[r] & 0xffff);
            hHi[mr4 + r][j1] = (unsigned short)(pk1[r] >> 16);
            hLo[mr4 + r][j1] = (unsigned short)(pk1[r] & 0xffff);
        }
        // hs stores (plain, off critical path)
        #pragma unroll
        for (int r = 0; r < 4; r++) {
            size_t row = (size_t)t * 64 + g * 16 + mr4 + r;
            hs[row * 512 + j0] = (unsigned short)(pk0[r] >> 16);
            hs[row * 512 + j1] = (unsigned short)(pk1[r] >> 16);
        }
        #pragma unroll
        for (int r = 0; r < 4; r++) { xv0[r] = xn0[r]; xv1[r] = xn1[r]; }

        // wait for ALL 8 peer waves (acquire: progress + orders data loads after)
        {
            const int* fb = &flags[(g * 2 + p1i) * 8 + (l & 7)];
            while (true) {
                int v = t + 1;
                if (l < 8) v = __hip_atomic_load(fb, __ATOMIC_ACQUIRE, __HIP_MEMORY_SCOPE_AGENT);
                if (__ballot(v < t + 1) == 0ull) break;
                __builtin_amdgcn_s_sleep(1);
            }
        }
        // consume peer slice: 2048 u64 (256 cols x 8 rowpairs), 4 per thread
        {
            int cl = tid >> 1, hh = tid & 1;
            size_t base = ((size_t)(g * 2 + par) * 512 + p1i * 256 + cl) * 8 + hh * 4;
            unsigned long long q[4];
            #pragma unroll
            for (int e = 0; e < 4; e++)
                q[e] = __hip_atomic_load(&hbuf64[base + e], __ATOMIC_RELAXED, __HIP_MEMORY_SCOPE_AGENT);
            int col = p1i * 256 + cl;
            #pragma unroll
            for (int e = 0; e < 4; e++) {
                int row = hh * 8 + e * 2;
                unsigned lo32 = (unsigned)q[e], hi32 = (unsigned)(q[e] >> 32);
                hHi[row][col]     = (unsigned short)(lo32 >> 16);
                hLo[row][col]     = (unsigned short)(lo32 & 0xffff);
                hHi[row + 1][col] = (unsigned short)(hi32 >> 16);
                hLo[row + 1][col] = (unsigned short)(hi32 & 0xffff);
            }
        }
        __syncthreads();                        // LDS h_{t+1} ready
    }
}

// ---------------------------------------------------------------- launch
extern "C" void kernel_launch(void* const* d_in, const int* in_sizes, int n_in,
                              void* d_out, int out_size, void* d_ws, size_t ws_size,
                              hipStream_t stream) {
    const float* x   = (const float*)d_in[0];
    const float* Wi  = (const float*)d_in[1];
    const float* bi  = (const float*)d_in[2];
    const float* Wr  = (const float*)d_in[3];
    const float* br  = (const float*)d_in[4];
    const float* tau = (const float*)d_in[5];
    const float* Wo  = (const float*)d_in[6];
    const float* bo  = (const float*)d_in[7];

    float* out    = (float*)d_out;
    float* xin    = (float*)d_out;                       // reuse outs region for xin [S,B,H] fp32
    float* hfinal = (float*)d_out + (size_t)33554432;    // after B*S*DOUT

    // ws: hs bf16 [S,B,H] (64 MiB) | hbuf64 u64 [4][2][512][8] (256 KiB) | flags[64]
    unsigned short* hs        = (unsigned short*)d_ws;
    unsigned long long* hbuf64 = (unsigned long long*)((char*)d_ws + (size_t)67108864);
    int* flags                = (int*)((char*)d_ws + (size_t)67108864 + 262144);

    hipLaunchKernelGGL(init_flags, dim3(1), dim3(64), 0, stream, flags);
    hipLaunchKernelGGL(gemm_xin, dim3(512, 4), dim3(256), 0, stream, x, Wi, bi, xin);
    hipLaunchKernelGGL(scan_k, dim3(8), dim3(512), 0, stream,
                       Wr, br, tau, xin, hs, hbuf64, flags, hfinal);
    hipLaunchKernelGGL(gemm_out, dim3(512, 4), dim3(256), 0, stream, hs, Wo, bo, out);
}

// Round 5
// 4356.148 us; speedup vs baseline: 1.6080x; 1.3948x over previous
//
#include <hip/hip_runtime.h>
#include <hip/hip_bf16.h>

// LiquidLinear: xin = x@Wi^T + bi ; scan: h' = (1-sig(tau))h + sig(tau)tanh(xin_t + h@Wr^T + br)
// outs = hs@Wo^T + bo ; outputs = [outs (B,S,DOUT) fp32][h_final (B,H) fp32]
// B=64 S=1024 DIN=H=DOUT=512
//
// R5: R4 structure, but the cross-block protocol is pure atomic-RMW (no release/
// acquire -> no buffer_wbl2 / buffer_inv cache walks, which were ~5.8us/step in R4).
//  - publish: u64 atomic_exchange (performed at IF; return makes vmcnt track completion)
//  - order:   s_waitcnt vmcnt(0) per wave, then u32 flag atomic_exchange
//  - poll:    atomic_fetch_add(flag, 0)  (RMW -> always IF-fresh, no inv needed)
//  - consume: atomic_fetch_add(data, 0)  (issued after successful poll -> fresh)
// Parity double-buffer safety as R4: peer flag >= t+1 implies its step-t consume
// RMWs returned (they precede its flag swap in program order + vmcnt).

typedef short bf16x8 __attribute__((ext_vector_type(8)));
typedef float f32x4 __attribute__((ext_vector_type(4)));
typedef float floatv4 __attribute__((ext_vector_type(4)));
typedef unsigned short ushort4v __attribute__((ext_vector_type(4)));

#define NSTEP 1024

__device__ __forceinline__ unsigned short f2bf(float f) {
    union { float f; unsigned u; } v; v.f = f;
    unsigned r = v.u + 0x7FFF + ((v.u >> 16) & 1);   // RNE
    return (unsigned short)(r >> 16);
}
__device__ __forceinline__ float bf2f(unsigned short u) {
    union { unsigned u; float f; } v; v.u = ((unsigned)u) << 16;
    return v.f;
}
__device__ __forceinline__ void vm_drain() {
    asm volatile("s_waitcnt vmcnt(0)" ::: "memory");
    __builtin_amdgcn_sched_barrier(0);
}

// ---------------------------------------------------------------- init control memory
__global__ void init_flags(int* flags) {
    int i = threadIdx.x;
    if (i < 64) flags[i] = 0;   // kernel-end writeback makes these visible to IF atomics
}

// ---------------------------------------------------------------- GEMM1: xin = x @ Wi^T + bi
__global__ __launch_bounds__(256) void gemm_xin(
    const float* __restrict__ X, const float* __restrict__ Wi,
    const float* __restrict__ bi, float* __restrict__ xin)
{
    __shared__ unsigned short As[128][40];
    __shared__ unsigned short Bs[128][40];
    const int bm = blockIdx.x, bn = blockIdx.y;
    const int tid = threadIdx.x, w = tid >> 6, l = tid & 63;
    const int wm = w >> 1, wn = w & 1;
    f32x4 acc[4][4] = {};

    for (int kt = 0; kt < 512; kt += 32) {
        __syncthreads();
        #pragma unroll
        for (int j = 0; j < 4; j++) {
            int q = tid + 256 * j;
            int row = q >> 3, c4 = (q & 7) * 4;
            floatv4 va = *(const floatv4*)&X[(size_t)(bm * 128 + row) * 512 + kt + c4];
            floatv4 vb = *(const floatv4*)&Wi[(size_t)(bn * 128 + row) * 512 + kt + c4];
            ushort4v pa, pb;
            #pragma unroll
            for (int e = 0; e < 4; e++) { pa[e] = f2bf(va[e]); pb[e] = f2bf(vb[e]); }
            *(ushort4v*)&As[row][c4] = pa;
            *(ushort4v*)&Bs[row][c4] = pb;
        }
        __syncthreads();
        bf16x8 a[4], b[4];
        #pragma unroll
        for (int i = 0; i < 4; i++)
            a[i] = *(const bf16x8*)&As[wm * 64 + i * 16 + (l & 15)][(l >> 4) * 8];
        #pragma unroll
        for (int i = 0; i < 4; i++)
            b[i] = *(const bf16x8*)&Bs[wn * 64 + i * 16 + (l & 15)][(l >> 4) * 8];
        #pragma unroll
        for (int i = 0; i < 4; i++)
            #pragma unroll
            for (int j = 0; j < 4; j++)
                acc[i][j] = __builtin_amdgcn_mfma_f32_16x16x32_bf16(a[i], b[j], acc[i][j], 0, 0, 0);
    }
    #pragma unroll
    for (int i = 0; i < 4; i++)
        #pragma unroll
        for (int j = 0; j < 4; j++)
            #pragma unroll
            for (int r = 0; r < 4; r++) {
                int m = bm * 128 + wm * 64 + i * 16 + (l >> 4) * 4 + r;
                int n = bn * 128 + wn * 64 + j * 16 + (l & 15);
                int bb = m >> 10, tt = m & 1023;
                xin[((size_t)tt * 64 + bb) * 512 + n] = acc[i][j][r] + bi[n];
            }
}

// ---------------------------------------------------------------- GEMM3: outs = hs @ Wo^T + bo
__global__ __launch_bounds__(256) void gemm_out(
    const unsigned short* __restrict__ hs, const float* __restrict__ Wo,
    const float* __restrict__ bo, float* __restrict__ out)
{
    __shared__ unsigned short As[128][40];
    __shared__ unsigned short Bs[128][40];
    const int bm = blockIdx.x, bn = blockIdx.y;
    const int tid = threadIdx.x, w = tid >> 6, l = tid & 63;
    const int wm = w >> 1, wn = w & 1;
    f32x4 acc[4][4] = {};

    for (int kt = 0; kt < 512; kt += 32) {
        __syncthreads();
        #pragma unroll
        for (int j = 0; j < 2; j++) {
            int q = tid + 256 * j;
            int row = q >> 2, c8 = (q & 3) * 8;
            int r = bm * 128 + row;
            int ra = (r & 1023) * 64 + (r >> 10);
            bf16x8 v = *(const bf16x8*)&hs[(size_t)ra * 512 + kt + c8];
            *(bf16x8*)&As[row][c8] = v;
        }
        #pragma unroll
        for (int j = 0; j < 4; j++) {
            int q = tid + 256 * j;
            int row = q >> 3, c4 = (q & 7) * 4;
            floatv4 vb = *(const floatv4*)&Wo[(size_t)(bn * 128 + row) * 512 + kt + c4];
            ushort4v pb;
            #pragma unroll
            for (int e = 0; e < 4; e++) pb[e] = f2bf(vb[e]);
            *(ushort4v*)&Bs[row][c4] = pb;
        }
        __syncthreads();
        bf16x8 a[4], b[4];
        #pragma unroll
        for (int i = 0; i < 4; i++)
            a[i] = *(const bf16x8*)&As[wm * 64 + i * 16 + (l & 15)][(l >> 4) * 8];
        #pragma unroll
        for (int i = 0; i < 4; i++)
            b[i] = *(const bf16x8*)&Bs[wn * 64 + i * 16 + (l & 15)][(l >> 4) * 8];
        #pragma unroll
        for (int i = 0; i < 4; i++)
            #pragma unroll
            for (int j = 0; j < 4; j++)
                acc[i][j] = __builtin_amdgcn_mfma_f32_16x16x32_bf16(a[i], b[j], acc[i][j], 0, 0, 0);
    }
    #pragma unroll
    for (int i = 0; i < 4; i++)
        #pragma unroll
        for (int j = 0; j < 4; j++)
            #pragma unroll
            for (int r = 0; r < 4; r++) {
                int m = bm * 128 + wm * 64 + i * 16 + (l >> 4) * 4 + r;
                int n = bn * 128 + wn * 64 + j * 16 + (l & 15);
                out[(size_t)m * 512 + n] = acc[i][j][r] + bo[n];
            }
}

// ---------------------------------------------------------------- scan
// 8 blocks: group g = bid&3 (16 batches), slice sl = bid>>2 (256 cols).
// hbuf64: u64 [4 group][2 par][512 col][8 rowpair]; value = rows (2rp,2rp+1)
// each packed (bf16hi<<16)|bf16lo. flags[(g*2+sl)*8+wave] monotonic counters.
__global__ __launch_bounds__(512, 2) void scan_k(
    const float* __restrict__ Wr, const float* __restrict__ brv,
    const float* __restrict__ tau, const float* __restrict__ xin,
    unsigned short* __restrict__ hs, unsigned long long* __restrict__ hbuf64,
    int* __restrict__ flags, float* __restrict__ hfinal)
{
    const int g  = blockIdx.x & 3;
    const int sl = blockIdx.x >> 2;      // 0..1
    const int tid = threadIdx.x, w = tid >> 6, l = tid & 63;

    __shared__ unsigned short hHi[16][520];
    __shared__ unsigned short hLo[16][520];
    for (int i = tid; i < 16 * 520; i += 512) { (&hHi[0][0])[i] = 0; (&hLo[0][0])[i] = 0; }

    // register-stationary Wr slice: wave owns 32 cols (two 16-col MFMA n-tiles)
    const int j0 = sl * 256 + w * 32 + (l & 15);
    const int j1 = j0 + 16;
    bf16x8 wf0[16], wf1[16];
    #pragma unroll
    for (int kt = 0; kt < 16; kt++) {
        const float* p0 = &Wr[(size_t)j0 * 512 + kt * 32 + (l >> 4) * 8];
        const float* p1 = &Wr[(size_t)j1 * 512 + kt * 32 + (l >> 4) * 8];
        bf16x8 f0, f1;
        #pragma unroll
        for (int e = 0; e < 8; e++) { f0[e] = (short)f2bf(p0[e]); f1[e] = (short)f2bf(p1[e]); }
        wf0[kt] = f0; wf1[kt] = f1;
    }
    const float d0 = 1.f / (1.f + __expf(-tau[j0])), d0c = 1.f - d0, br0 = brv[j0];
    const float d1 = 1.f / (1.f + __expf(-tau[j1])), d1c = 1.f - d1, br1 = brv[j1];
    float hold0[4] = {}, hold1[4] = {};
    const int mr4 = (l >> 4) * 4;             // this thread's 4 batch rows (local 0..15)
    const int p1i = 1 - sl;

    __syncthreads();

    // prologue xin for t=0
    float xv0[4], xv1[4], xn0[4], xn1[4];
    #pragma unroll
    for (int r = 0; r < 4; r++) {
        xv0[r] = xin[((size_t)0 * 64 + g * 16 + mr4 + r) * 512 + j0];
        xv1[r] = xin[((size_t)0 * 64 + g * 16 + mr4 + r) * 512 + j1];
    }

    for (int t = 0; t < NSTEP; ++t) {
        // prefetch next-step xin early (HBM latency hides under MFMA phase)
        if (t + 1 < NSTEP) {
            #pragma unroll
            for (int r = 0; r < 4; r++) {
                xn0[r] = xin[((size_t)(t + 1) * 64 + g * 16 + mr4 + r) * 512 + j0];
                xn1[r] = xin[((size_t)(t + 1) * 64 + g * 16 + mr4 + r) * 512 + j1];
            }
        }
        // I = h @ WrSlice^T (hi + lo passes, 4 independent acc chains)
        f32x4 aA0 = {}, aB0 = {}, aA1 = {}, aB1 = {};
        #pragma unroll
        for (int kt = 0; kt < 16; kt++) {
            bf16x8 ah = *(const bf16x8*)&hHi[l & 15][kt * 32 + (l >> 4) * 8];
            bf16x8 al = *(const bf16x8*)&hLo[l & 15][kt * 32 + (l >> 4) * 8];
            aA0 = __builtin_amdgcn_mfma_f32_16x16x32_bf16(ah, wf0[kt], aA0, 0, 0, 0);
            aB0 = __builtin_amdgcn_mfma_f32_16x16x32_bf16(al, wf0[kt], aB0, 0, 0, 0);
            aA1 = __builtin_amdgcn_mfma_f32_16x16x32_bf16(ah, wf1[kt], aA1, 0, 0, 0);
            aB1 = __builtin_amdgcn_mfma_f32_16x16x32_bf16(al, wf1[kt], aB1, 0, 0, 0);
        }

        float hn0[4], hn1[4];
        #pragma unroll
        for (int r = 0; r < 4; r++) {
            float I0 = aA0[r] + aB0[r] + xv0[r] + br0;
            float I1 = aA1[r] + aB1[r] + xv1[r] + br1;
            hn0[r] = d0c * hold0[r] + d0 * tanhf(I0); hold0[r] = hn0[r];
            hn1[r] = d1c * hold1[r] + d1 * tanhf(I1); hold1[r] = hn1[r];
        }
        if (t == NSTEP - 1) {
            #pragma unroll
            for (int r = 0; r < 4; r++) {
                size_t row = (size_t)t * 64 + g * 16 + mr4 + r;
                hs[row * 512 + j0] = f2bf(hn0[r]);
                hs[row * 512 + j1] = f2bf(hn1[r]);
                hfinal[(size_t)(g * 16 + mr4 + r) * 512 + j0] = hold0[r];
                hfinal[(size_t)(g * 16 + mr4 + r) * 512 + j1] = hold1[r];
            }
            break;
        }
        const int par = (t + 1) & 1;

        // pack hi/lo
        unsigned pk0[4], pk1[4];
        #pragma unroll
        for (int r = 0; r < 4; r++) {
            unsigned short h0 = f2bf(hn0[r]), lo0 = f2bf(hn0[r] - bf2f(h0));
            unsigned short h1 = f2bf(hn1[r]), lo1 = f2bf(hn1[r] - bf2f(h1));
            pk0[r] = ((unsigned)h0 << 16) | lo0;
            pk1[r] = ((unsigned)h1 << 16) | lo1;
        }
        // publish own slice: 4 u64 atomic swaps (performed at IF; returns tracked by vmcnt)
        {
            unsigned long long q00 = (unsigned long long)pk0[0] | ((unsigned long long)pk0[1] << 32);
            unsigned long long q01 = (unsigned long long)pk0[2] | ((unsigned long long)pk0[3] << 32);
            unsigned long long q10 = (unsigned long long)pk1[0] | ((unsigned long long)pk1[1] << 32);
            unsigned long long q11 = (unsigned long long)pk1[2] | ((unsigned long long)pk1[3] << 32);
            size_t b0 = ((size_t)(g * 2 + par) * 512 + j0) * 8 + (mr4 >> 1);
            size_t b1 = ((size_t)(g * 2 + par) * 512 + j1) * 8 + (mr4 >> 1);
            (void)__hip_atomic_exchange(&hbuf64[b0],     q00, __ATOMIC_RELAXED, __HIP_MEMORY_SCOPE_AGENT);
            (void)__hip_atomic_exchange(&hbuf64[b0 + 1], q01, __ATOMIC_RELAXED, __HIP_MEMORY_SCOPE_AGENT);
            (void)__hip_atomic_exchange(&hbuf64[b1],     q10, __ATOMIC_RELAXED, __HIP_MEMORY_SCOPE_AGENT);
            (void)__hip_atomic_exchange(&hbuf64[b1 + 1], q11, __ATOMIC_RELAXED, __HIP_MEMORY_SCOPE_AGENT);
        }
        vm_drain();   // wave's data swaps performed at IF
        if (l == 0)
            (void)__hip_atomic_exchange(&flags[(g * 2 + sl) * 8 + w], t + 1,
                                        __ATOMIC_RELAXED, __HIP_MEMORY_SCOPE_AGENT);

        __syncthreads();                       // all waves done reading LDS h_t
        // own slice into LDS
        #pragma unroll
        for (int r = 0; r < 4; r++) {
            hHi[mr4 + r][j0] = (unsigned short)(pk0[r] >> 16);
            hLo[mr4 + r][j0] = (unsigned short)(pk0[r] & 0xffff);
            hHi[mr4 + r][j1] = (unsigned short)(pk1[r] >> 16);
            hLo[mr4 + r][j1] = (unsigned short)(pk1[r] & 0xffff);
        }
        // hs stores (plain cacheable; no wbl2 anywhere, so these are off-path)
        #pragma unroll
        for (int r = 0; r < 4; r++) {
            size_t row = (size_t)t * 64 + g * 16 + mr4 + r;
            hs[row * 512 + j0] = (unsigned short)(pk0[r] >> 16);
            hs[row * 512 + j1] = (unsigned short)(pk1[r] >> 16);
        }
        #pragma unroll
        for (int r = 0; r < 4; r++) { xv0[r] = xn0[r]; xv1[r] = xn1[r]; }

        // wait for ALL 8 peer waves via RMW polls (always IF-fresh, no cache inv)
        {
            int* fb = &flags[(g * 2 + p1i) * 8 + (l & 7)];
            while (true) {
                int v = t + 1;
                if (l < 8) v = __hip_atomic_fetch_add(fb, 0, __ATOMIC_RELAXED, __HIP_MEMORY_SCOPE_AGENT);
                if (__ballot(v < t + 1) == 0ull) break;
                __builtin_amdgcn_s_sleep(1);
            }
        }
        // consume peer slice: 2048 u64 RMW reads (256 cols x 8 rowpairs), 4 per thread
        {
            int cl = tid >> 1, hh = tid & 1;
            size_t base = ((size_t)(g * 2 + par) * 512 + p1i * 256 + cl) * 8 + hh * 4;
            unsigned long long q[4];
            #pragma unroll
            for (int e = 0; e < 4; e++)
                q[e] = __hip_atomic_fetch_add(&hbuf64[base + e], 0ULL,
                                              __ATOMIC_RELAXED, __HIP_MEMORY_SCOPE_AGENT);
            int col = p1i * 256 + cl;
            #pragma unroll
            for (int e = 0; e < 4; e++) {
                int row = hh * 8 + e * 2;
                unsigned lo32 = (unsigned)q[e], hi32 = (unsigned)(q[e] >> 32);
                hHi[row][col]     = (unsigned short)(lo32 >> 16);
                hLo[row][col]     = (unsigned short)(lo32 & 0xffff);
                hHi[row + 1][col] = (unsigned short)(hi32 >> 16);
                hLo[row + 1][col] = (unsigned short)(hi32 & 0xffff);
            }
        }
        __syncthreads();                        // LDS h_{t+1} ready
    }
}

// ---------------------------------------------------------------- launch
extern "C" void kernel_launch(void* const* d_in, const int* in_sizes, int n_in,
                              void* d_out, int out_size, void* d_ws, size_t ws_size,
                              hipStream_t stream) {
    const float* x   = (const float*)d_in[0];
    const float* Wi  = (const float*)d_in[1];
    const float* bi  = (const float*)d_in[2];
    const float* Wr  = (const float*)d_in[3];
    const float* br  = (const float*)d_in[4];
    const float* tau = (const float*)d_in[5];
    const float* Wo  = (const float*)d_in[6];
    const float* bo  = (const float*)d_in[7];

    float* out    = (float*)d_out;
    float* xin    = (float*)d_out;                       // reuse outs region for xin [S,B,H] fp32
    float* hfinal = (float*)d_out + (size_t)33554432;    // after B*S*DOUT

    // ws: hs bf16 [S,B,H] (64 MiB) | hbuf64 u64 [4][2][512][8] (256 KiB) | flags[64]
    unsigned short* hs        = (unsigned short*)d_ws;
    unsigned long long* hbuf64 = (unsigned long long*)((char*)d_ws + (size_t)67108864);
    int* flags                = (int*)((char*)d_ws + (size_t)67108864 + 262144);

    hipLaunchKernelGGL(init_flags, dim3(1), dim3(64), 0, stream, flags);
    hipLaunchKernelGGL(gemm_xin, dim3(512, 4), dim3(256), 0, stream, x, Wi, bi, xin);
    hipLaunchKernelGGL(scan_k, dim3(8), dim3(512), 0, stream,
                       Wr, br, tau, xin, hs, hbuf64, flags, hfinal);
    hipLaunchKernelGGL(gemm_out, dim3(512, 4), dim3(256), 0, stream, hs, Wo, bo, out);
}